// Round 1
// 286.215 us; speedup vs baseline: 1.0232x; 1.0232x over previous
//
#include <hip/hip_runtime.h>
#include <hip/hip_bf16.h>
#include <math.h>

#define B_SZ    1024
#define DI      2560
#define DS      16
#define DR      160
#define NPROJ   192   // DR + DS + DS

typedef __bf16 bf16x8 __attribute__((ext_vector_type(8)));
typedef __bf16 bf16x4 __attribute__((ext_vector_type(4)));
typedef float  f32x4  __attribute__((ext_vector_type(4)));

// ---------------- kernel 0: fp32 -> bf16 conversions + negA = -exp(A_log) ----
// vectorized x4: all section sizes are multiples of 4
__device__ __forceinline__ void cvt4(const float* __restrict__ s,
                                     __bf16* __restrict__ d, int i) {
  float4 v = *(const float4*)(s + i);
  bf16x4 o = { (__bf16)v.x, (__bf16)v.y, (__bf16)v.z, (__bf16)v.w };
  *(bf16x4*)(d + i) = o;
}

__global__ void __launch_bounds__(256) convert_kernel(
    const float* __restrict__ x, const float* __restrict__ Wdl,
    const float* __restrict__ WB, const float* __restrict__ WC,
    const float* __restrict__ Wdt, const float* __restrict__ A_log,
    __bf16* __restrict__ xb, __bf16* __restrict__ wcat,
    __bf16* __restrict__ wdtb, float* __restrict__ negA) {
  int i = (blockIdx.x * 256 + threadIdx.x) * 4;
  const int NX   = B_SZ * DI;   // 2621440
  const int NWDL = DR * DI;     // 409600
  const int NWB  = DS * DI;     // 40960
  const int NWDT = DI * DR;     // 409600
  const int NA   = DI * DS;     // 40960
  if (i < NX)   { cvt4(x, xb, i); return; }
  i -= NX;
  if (i < NWDL) { cvt4(Wdl, wcat, i); return; }
  i -= NWDL;
  if (i < NWB)  { cvt4(WB, wcat + NWDL, i); return; }
  i -= NWB;
  if (i < NWB)  { cvt4(WC, wcat + NWDL + NWB, i); return; }
  i -= NWB;
  if (i < NWDT) { cvt4(Wdt, wdtb, i); return; }
  i -= NWDT;
  if (i < NA) {
    float4 v = *(const float4*)(A_log + i);
    float4 o = { -__expf(v.x), -__expf(v.y), -__expf(v.z), -__expf(v.w) };
    *(float4*)(negA + i) = o;
  }
}

// ---------------- kernel 1: proj GEMM  C[1024,192] = xb . wcat^T -------------
// per-wave 16x16 tile, K=2560 in 80 MFMA steps, no LDS (L2-bound, ~3.6us)
__global__ void __launch_bounds__(256) proj_kernel(
    const __bf16* __restrict__ xb, const __bf16* __restrict__ wcat,
    __bf16* __restrict__ dtlow, float* __restrict__ Bt, float* __restrict__ Ct) {
  int gw    = blockIdx.x * 4 + (threadIdx.x >> 6);   // 768 wave-tiles
  int lane  = threadIdx.x & 63;
  int mtile = gw & 63;       // 64 m-tiles of 16
  int ntile = gw >> 6;       // 12 n-tiles of 16
  int b0 = mtile * 16, n0 = ntile * 16;
  int m = lane & 15, quad = lane >> 4;
  const __bf16* ap = xb   + (size_t)(b0 + m) * DI + quad * 8;
  const __bf16* bp = wcat + (size_t)(n0 + m) * DI + quad * 8;  // n-index = lane&15
  f32x4 acc = {0.f, 0.f, 0.f, 0.f};
  for (int k0 = 0; k0 < DI; k0 += 32) {
    bf16x8 a = *(const bf16x8*)(ap + k0);
    bf16x8 b = *(const bf16x8*)(bp + k0);
    acc = __builtin_amdgcn_mfma_f32_16x16x32_bf16(a, b, acc, 0, 0, 0);
  }
  // D layout: col = lane&15 (n), row = quad*4 + r (m)   [verified mapping]
  int nn = n0 + m;
#pragma unroll
  for (int r = 0; r < 4; ++r) {
    int bb = b0 + quad * 4 + r;
    float v = acc[r];
    if (nn < DR)            dtlow[bb * DR + nn] = (__bf16)v;
    else if (nn < DR + DS)  Bt[bb * DS + (nn - DR)] = v;
    else                    Ct[bb * DS + (nn - DR - DS)] = v;
  }
}

// ---------------- kernel 2: fused dt GEMM + softplus + SSM h pass ------------
// per wave-tile (16 b x 16 d): dt[b,d] = softplus(dtlow[b,:].Wdt[d,:] + b_dt),
// then y[b,d] = sum_n (exp(dt*A[d,n])*h[b,d,n] + dt*Bt[b,n]*x[b,d])*Ct[b,n] + D[d]*x
// dt never touches HBM (saves 21 MB round-trip vs split kernels).
__global__ void __launch_bounds__(256) dtssm_kernel(
    const __bf16* __restrict__ dtlow, const __bf16* __restrict__ wdtb,
    const float* __restrict__ b_dt,
    const float* __restrict__ x, const float* __restrict__ h,
    const float* __restrict__ negA, const float* __restrict__ Bt,
    const float* __restrict__ Ct, const float* __restrict__ Dp,
    float* __restrict__ y) {
  int gw    = blockIdx.x * 4 + (threadIdx.x >> 6);   // 10240 wave-tiles
  int lane  = threadIdx.x & 63;
  int mtile = gw & 63;       // 64 m-tiles (batch)
  int ntile = gw >> 6;       // 160 n-tiles (d_inner)
  int b0 = mtile * 16, d0 = ntile * 16;
  int m = lane & 15, quad = lane >> 4;
  const __bf16* ap = dtlow + (size_t)(b0 + m) * DR + quad * 8;
  const __bf16* bp = wdtb  + (size_t)(d0 + m) * DR + quad * 8;
  f32x4 acc = {0.f, 0.f, 0.f, 0.f};
#pragma unroll
  for (int k0 = 0; k0 < DR; k0 += 32) {
    bf16x8 a = *(const bf16x8*)(ap + k0);
    bf16x8 b = *(const bf16x8*)(bp + k0);
    acc = __builtin_amdgcn_mfma_f32_16x16x32_bf16(a, b, acc, 0, 0, 0);
  }
  // D layout: col = lane&15 -> d index; row = quad*4 + r -> b index
  int dd = d0 + m;
  float bias = b_dt[dd];
  float dval = Dp[dd];
  // negA[dd,:] is shared by all 4 batch rows this thread owns -> load once
  const float4* a4 = (const float4*)(negA + (size_t)dd * DS);
  float4 av0 = a4[0], av1 = a4[1], av2 = a4[2], av3 = a4[3];
#pragma unroll
  for (int r = 0; r < 4; ++r) {
    int bb = b0 + quad * 4 + r;
    size_t e = (size_t)bb * DI + dd;
    float z = acc[r] + bias;
    float dtv = (z > 20.f) ? z : log1pf(__expf(z));
    float xv  = x[e];
    float dtl = dtv * 1.44269504f;   // dt * log2(e), for exp2
    float dxv = dtv * xv;
    const float4* h4 = (const float4*)(h  + e * DS);
    const float4* b4 = (const float4*)(Bt + (size_t)bb * DS);
    const float4* c4 = (const float4*)(Ct + (size_t)bb * DS);
    float s = 0.f;
    {
      float4 hv = h4[0], bv = b4[0], cv = c4[0];
      s += (exp2f(av0.x * dtl) * hv.x + bv.x * dxv) * cv.x;
      s += (exp2f(av0.y * dtl) * hv.y + bv.y * dxv) * cv.y;
      s += (exp2f(av0.z * dtl) * hv.z + bv.z * dxv) * cv.z;
      s += (exp2f(av0.w * dtl) * hv.w + bv.w * dxv) * cv.w;
    }
    {
      float4 hv = h4[1], bv = b4[1], cv = c4[1];
      s += (exp2f(av1.x * dtl) * hv.x + bv.x * dxv) * cv.x;
      s += (exp2f(av1.y * dtl) * hv.y + bv.y * dxv) * cv.y;
      s += (exp2f(av1.z * dtl) * hv.z + bv.z * dxv) * cv.z;
      s += (exp2f(av1.w * dtl) * hv.w + bv.w * dxv) * cv.w;
    }
    {
      float4 hv = h4[2], bv = b4[2], cv = c4[2];
      s += (exp2f(av2.x * dtl) * hv.x + bv.x * dxv) * cv.x;
      s += (exp2f(av2.y * dtl) * hv.y + bv.y * dxv) * cv.y;
      s += (exp2f(av2.z * dtl) * hv.z + bv.z * dxv) * cv.z;
      s += (exp2f(av2.w * dtl) * hv.w + bv.w * dxv) * cv.w;
    }
    {
      float4 hv = h4[3], bv = b4[3], cv = c4[3];
      s += (exp2f(av3.x * dtl) * hv.x + bv.x * dxv) * cv.x;
      s += (exp2f(av3.y * dtl) * hv.y + bv.y * dxv) * cv.y;
      s += (exp2f(av3.z * dtl) * hv.z + bv.z * dxv) * cv.z;
      s += (exp2f(av3.w * dtl) * hv.w + bv.w * dxv) * cv.w;
    }
    y[e] = s + dval * xv;
  }
}

extern "C" void kernel_launch(void* const* d_in, const int* in_sizes, int n_in,
                              void* d_out, int out_size, void* d_ws, size_t ws_size,
                              hipStream_t stream) {
  const float* x     = (const float*)d_in[0];
  const float* h     = (const float*)d_in[1];
  const float* Wdl   = (const float*)d_in[2];
  const float* Wdt   = (const float*)d_in[3];
  const float* b_dt  = (const float*)d_in[4];
  const float* WB    = (const float*)d_in[5];
  const float* WC    = (const float*)d_in[6];
  const float* A_log = (const float*)d_in[7];
  const float* Dp    = (const float*)d_in[8];
  float* y = (float*)d_out;

  // workspace layout (all offsets 256B-aligned); dt buffer eliminated
  char* ws = (char*)d_ws;
  __bf16* xb    = (__bf16*)(ws);                       // 5,242,880 B
  __bf16* wcat  = (__bf16*)(ws + 5242880);             //   983,040 B
  __bf16* wdtb  = (__bf16*)(ws + 6225920);             //   819,200 B
  float*  negA  = (float*) (ws + 7045120);             //   163,840 B
  __bf16* dtlow = (__bf16*)(ws + 7208960);             //   327,680 B
  float*  Bt    = (float*) (ws + 7536640);             //    65,536 B
  float*  Ct    = (float*) (ws + 7602176);             //    65,536 B -> total 7,667,712
  if (ws_size < 7667712) return;  // workspace too small (would corrupt)

  // k0: conversions, x4 vectorized. 3,563,520 elems / 4 = 890,880 thr -> 3480 blocks
  convert_kernel<<<3480, 256, 0, stream>>>(x, Wdl, WB, WC, Wdt, A_log,
                                           xb, wcat, wdtb, negA);
  // k1: 768 wave-tiles / 4 waves per block
  proj_kernel<<<192, 256, 0, stream>>>(xb, wcat, dtlow, Bt, Ct);
  // k2: fused dt-GEMM + SSM, 10240 wave-tiles / 4 waves per block
  dtssm_kernel<<<2560, 256, 0, stream>>>(dtlow, wdtb, b_dt, x, h, negA,
                                         Bt, Ct, Dp, y);
}